// Round 1
// baseline (635.241 us; speedup 1.0000x reference)
//
#include <hip/hip_runtime.h>
#include <hip/hip_bf16.h>
#include <stdint.h>

#define NROW 8192
#define CD 128
#define SPLITK 8
#define KCHUNK (NROW / SPLITK)

typedef __bf16 bf16_t;
typedef __bf16 bf16x8 __attribute__((ext_vector_type(8)));
typedef float f32x4 __attribute__((ext_vector_type(4)));

__device__ __forceinline__ f32x4 mfma16(bf16x8 a, bf16x8 b, f32x4 c) {
    return __builtin_amdgcn_mfma_f32_16x16x32_bf16(a, b, c, 0, 0, 0);
}

__device__ __forceinline__ bf16x8 load_cvt_bf16(const float* __restrict__ p) {
    float4 a0 = *(const float4*)p;
    float4 a1 = *(const float4*)(p + 4);
    bf16x8 r;
    r[0] = (bf16_t)a0.x; r[1] = (bf16_t)a0.y; r[2] = (bf16_t)a0.z; r[3] = (bf16_t)a0.w;
    r[4] = (bf16_t)a1.x; r[5] = (bf16_t)a1.y; r[6] = (bf16_t)a1.z; r[7] = (bf16_t)a1.w;
    return r;
}

__device__ __forceinline__ bf16x8 load_mul_bf16(const float* __restrict__ pa,
                                                const float* __restrict__ pm) {
    float4 a0 = *(const float4*)pa;
    float4 a1 = *(const float4*)(pa + 4);
    float4 b0 = *(const float4*)pm;
    float4 b1 = *(const float4*)(pm + 4);
    bf16x8 r;
    r[0] = (bf16_t)(a0.x * b0.x); r[1] = (bf16_t)(a0.y * b0.y);
    r[2] = (bf16_t)(a0.z * b0.z); r[3] = (bf16_t)(a0.w * b0.w);
    r[4] = (bf16_t)(a1.x * b1.x); r[5] = (bf16_t)(a1.y * b1.y);
    r[6] = (bf16_t)(a1.z * b1.z); r[7] = (bf16_t)(a1.w * b1.w);
    return r;
}

// h = x @ W^T. Writes h (fp32) to out — this is the identity (+I) contribution —
// and h^T (bf16, [c][n], k-contiguous for B-fragment loads) to hT.
__global__ void h_kernel(const float* __restrict__ x, const float* __restrict__ W,
                         bf16_t* __restrict__ hT, float* __restrict__ out)
{
    const int wave = threadIdx.x >> 6;
    const int lane = threadIdx.x & 63;
    const int m = lane & 15;
    const int q = lane >> 4;
    const int row_base = blockIdx.x * 128 + wave * 32;

    f32x4 acc[2][8] = {};

#pragma unroll
    for (int k0 = 0; k0 < CD; k0 += 32) {
        bf16x8 af[2];
#pragma unroll
        for (int r = 0; r < 2; ++r)
            af[r] = load_cvt_bf16(x + (size_t)(row_base + r * 16 + m) * CD + k0 + q * 8);
        bf16x8 bfr[8];
#pragma unroll
        for (int c = 0; c < 8; ++c)
            bfr[c] = load_cvt_bf16(W + (size_t)(c * 16 + m) * CD + k0 + q * 8);
#pragma unroll
        for (int r = 0; r < 2; ++r)
#pragma unroll
            for (int c = 0; c < 8; ++c)
                acc[r][c] = mfma16(af[r], bfr[c], acc[r][c]);
    }

#pragma unroll
    for (int r = 0; r < 2; ++r)
#pragma unroll
        for (int c = 0; c < 8; ++c) {
            const int col = c * 16 + m;
#pragma unroll
            for (int j = 0; j < 4; ++j) {
                const int row = row_base + r * 16 + q * 4 + j;
                const float v = acc[r][c][j];
                out[(size_t)row * CD + col] = v;
                hT[(size_t)col * NROW + row] = (bf16_t)v;
            }
        }
}

// out_partial(or out) += (adj .* mask) @ h  for one K-chunk.
// LDS-free: A-fragments built directly from coalesced global loads (fused mul+cvt),
// B-fragments straight dwordx4 from hT (L2-resident). No __syncthreads anywhere.
template <bool ATOMIC>
__global__ void gemm_kernel(const float* __restrict__ adj, const float* __restrict__ mask,
                            const bf16_t* __restrict__ hT, float* __restrict__ outp)
{
    const int wave = threadIdx.x >> 6;
    const int lane = threadIdx.x & 63;
    const int m = lane & 15;
    const int q = lane >> 4;
    const int row_base = blockIdx.x * 128 + wave * 32;
    const int s = blockIdx.y;
    const int kbeg = s * KCHUNK;

    f32x4 acc[2][8] = {};

    const float* pa0 = adj  + (size_t)(row_base + m) * NROW + kbeg + q * 8;
    const float* pa1 = adj  + (size_t)(row_base + 16 + m) * NROW + kbeg + q * 8;
    const float* pm0 = mask + (size_t)(row_base + m) * NROW + kbeg + q * 8;
    const float* pm1 = mask + (size_t)(row_base + 16 + m) * NROW + kbeg + q * 8;
    const bf16_t* pb[8];
#pragma unroll
    for (int c = 0; c < 8; ++c)
        pb[c] = hT + (size_t)(c * 16 + m) * NROW + kbeg + q * 8;

    for (int kk = 0; kk < KCHUNK; kk += 32) {
        bf16x8 af[2];
        af[0] = load_mul_bf16(pa0, pm0);
        af[1] = load_mul_bf16(pa1, pm1);
        pa0 += 32; pa1 += 32; pm0 += 32; pm1 += 32;

        bf16x8 bfr[8];
#pragma unroll
        for (int c = 0; c < 8; ++c) {
            bfr[c] = *(const bf16x8*)(pb[c]);
            pb[c] += 32;
        }

#pragma unroll
        for (int r = 0; r < 2; ++r)
#pragma unroll
            for (int c = 0; c < 8; ++c)
                acc[r][c] = mfma16(af[r], bfr[c], acc[r][c]);
    }

    float* obase = ATOMIC ? outp : outp + (size_t)s * ((size_t)NROW * CD);
#pragma unroll
    for (int r = 0; r < 2; ++r)
#pragma unroll
        for (int c = 0; c < 8; ++c) {
            const int col = c * 16 + m;
#pragma unroll
            for (int j = 0; j < 4; ++j) {
                const int row = row_base + r * 16 + q * 4 + j;
                const size_t idx = (size_t)row * CD + col;
                if (ATOMIC)
                    atomicAdd(outp + idx, acc[r][c][j]);
                else
                    obase[idx] = acc[r][c][j];
            }
        }
}

// out = out(h contribution) + sum over split-K partials
__global__ void reduce_kernel(float* __restrict__ out, const float* __restrict__ part)
{
    const size_t i = ((size_t)blockIdx.x * 256 + threadIdx.x) * 4;
    float4 sum = *(const float4*)(out + i);
#pragma unroll
    for (int sp = 0; sp < SPLITK; ++sp) {
        float4 p = *(const float4*)(part + (size_t)sp * ((size_t)NROW * CD) + i);
        sum.x += p.x; sum.y += p.y; sum.z += p.z; sum.w += p.w;
    }
    *(float4*)(out + i) = sum;
}

extern "C" void kernel_launch(void* const* d_in, const int* in_sizes, int n_in,
                              void* d_out, int out_size, void* d_ws, size_t ws_size,
                              hipStream_t stream)
{
    const float* x    = (const float*)d_in[0];
    const float* adj  = (const float*)d_in[1];
    const float* mask = (const float*)d_in[2];
    const float* W    = (const float*)d_in[3];
    float* out = (float*)d_out;

    bf16_t* hT = (bf16_t*)d_ws;  // 128 x 8192 bf16 = 2 MB
    const size_t HT_BYTES   = (size_t)CD * NROW * sizeof(bf16_t);
    const size_t PART_BYTES = (size_t)SPLITK * NROW * CD * sizeof(float);  // 32 MB

    // 1) h = x @ W^T  (writes identity contribution to out, h^T bf16 to ws)
    h_kernel<<<dim3(64), dim3(256), 0, stream>>>(x, W, hT, out);

    if (ws_size >= HT_BYTES + PART_BYTES) {
        // 2) split-K GEMM into fp32 partials (no atomics)
        float* part = (float*)((char*)d_ws + HT_BYTES);
        gemm_kernel<false><<<dim3(64, SPLITK), dim3(256), 0, stream>>>(adj, mask, hT, part);
        // 3) reduce partials onto out
        reduce_kernel<<<dim3(1024), dim3(256), 0, stream>>>(out, part);
    } else {
        // fallback: accumulate directly into out with device-scope fp32 atomics
        gemm_kernel<true><<<dim3(64, SPLITK), dim3(256), 0, stream>>>(adj, mask, hT, out);
    }
}

// Round 2
// 578.718 us; speedup vs baseline: 1.0977x; 1.0977x over previous
//
#include <hip/hip_runtime.h>
#include <hip/hip_bf16.h>
#include <stdint.h>

#define NROW 8192
#define CD 128
#define SPLITK 8
#define KCHUNK (NROW / SPLITK)   // 1024
#define BK 64
#define NITER (KCHUNK / BK)      // 16

typedef __bf16 bf16_t;
typedef __bf16 bf16x8 __attribute__((ext_vector_type(8)));
typedef __bf16 bf16x4 __attribute__((ext_vector_type(4)));
typedef float f32x4 __attribute__((ext_vector_type(4)));

__device__ __forceinline__ f32x4 mfma16(bf16x8 a, bf16x8 b, f32x4 c) {
    return __builtin_amdgcn_mfma_f32_16x16x32_bf16(a, b, c, 0, 0, 0);
}

// async global->LDS DMA, 16 B per lane; LDS dest must be wave-uniform base + lane*16
__device__ __forceinline__ void dma16(const void* g, void* l) {
    __builtin_amdgcn_global_load_lds(
        (const __attribute__((address_space(1))) uint32_t*)g,
        (__attribute__((address_space(3))) uint32_t*)l, 16, 0, 0);
}

__device__ __forceinline__ bf16x8 load_cvt_bf16(const float* __restrict__ p) {
    float4 a0 = *(const float4*)p;
    float4 a1 = *(const float4*)(p + 4);
    bf16x8 r;
    r[0] = (bf16_t)a0.x; r[1] = (bf16_t)a0.y; r[2] = (bf16_t)a0.z; r[3] = (bf16_t)a0.w;
    r[4] = (bf16_t)a1.x; r[5] = (bf16_t)a1.y; r[6] = (bf16_t)a1.z; r[7] = (bf16_t)a1.w;
    return r;
}

// h = x @ W^T. Block = 256 thr (4 waves x 16 rows). Epilogue via LDS transpose:
// out fp32 coalesced float4, hT [c][n] bf16 coalesced 16B stores.
__global__ __launch_bounds__(256)
void h_kernel(const float* __restrict__ x, const float* __restrict__ W,
              bf16_t* __restrict__ hT, float* __restrict__ out)
{
    __shared__ __align__(16) float h_sl_all[4][16 * 128];  // 32 KB
    const int tid = threadIdx.x;
    const int w = tid >> 6, lane = tid & 63;
    const int m = lane & 15, q = lane >> 4;
    const int rb = blockIdx.x * 64 + w * 16;   // wave's 16 rows

    f32x4 acc[8] = {};
#pragma unroll
    for (int k0 = 0; k0 < CD; k0 += 32) {
        bf16x8 af = load_cvt_bf16(x + (size_t)(rb + m) * CD + k0 + q * 8);
#pragma unroll
        for (int c = 0; c < 8; ++c) {
            bf16x8 bv = load_cvt_bf16(W + (size_t)(c * 16 + m) * CD + k0 + q * 8);
            acc[c] = mfma16(af, bv, acc[c]);
        }
    }
    float* hs = h_sl_all[w];
#pragma unroll
    for (int c = 0; c < 8; ++c)
#pragma unroll
        for (int j = 0; j < 4; ++j)
            hs[(q * 4 + j) * 128 + c * 16 + m] = acc[c][j];
    // per-wave private LDS region; compiler inserts lgkmcnt before reads

    float* dst = out + (size_t)rb * CD;
#pragma unroll
    for (int t = 0; t < 8; ++t) {
        int fi = t * 64 + lane;                 // 512 float4 = 16x128
        *(float4*)(dst + fi * 4) = *(const float4*)(hs + fi * 4);
    }
#pragma unroll
    for (int t = 0; t < 4; ++t) {
        int idx = t * 64 + lane;                // 256 chunks: 128 c x 2 n-chunks
        int c = idx >> 1, nc = idx & 1;
        bf16x8 v;
#pragma unroll
        for (int j = 0; j < 8; ++j)
            v[j] = (bf16_t)hs[(nc * 8 + j) * 128 + c];
        *(bf16x8*)(hT + (size_t)c * NROW + rb + nc * 8) = v;
    }
}

// out_partial = (adj .* mask) @ h for one K-chunk. 128-row M-tile, BK=64,
// double-buffered LDS (A: fused mul+cvt via VGPR; B: global_load_lds DMA).
// XOR swizzle chunk^(row&7) on 16B granules keeps fragment b128 reads spread
// over all 8 bank-quads (row stride = 128 B = exactly 32 banks otherwise).
template <bool ATOMIC>
__global__ __launch_bounds__(256)
void gemm_kernel(const float* __restrict__ adj, const float* __restrict__ mask,
                 const bf16_t* __restrict__ hT, float* __restrict__ outp)
{
    __shared__ __align__(16) ushort lds_all[32768];   // 64 KB
    ushort* const Ab0 = lds_all;                      // 16 KB each
    ushort* const Ab1 = lds_all + 8192;
    ushort* const Bb0 = lds_all + 16384;
    ushort* const Bb1 = lds_all + 24576;

    const int tid  = threadIdx.x;
    const int w    = tid >> 6;
    const int lane = tid & 63;
    const int m = lane & 15;
    const int q = lane >> 4;
    const int rowbase = blockIdx.x * 128;
    const int kbeg = blockIdx.y * KCHUNK;

    f32x4 acc[2][8] = {};
    float4 va[8], vm[8];   // staged adj/mask, held across compute for overlap

    auto loadA = [&](int it) {
        const int kw = kbeg + it * BK;
#pragma unroll
        for (int rr = 0; rr < 8; ++rr) {
            int idx = rr * 256 + tid;            // float4 index in 128x64 tile
            int row = idx >> 4, c4 = idx & 15;   // 16 float4 per row
            va[rr] = *(const float4*)(adj  + (size_t)(rowbase + row) * NROW + kw + c4 * 4);
            vm[rr] = *(const float4*)(mask + (size_t)(rowbase + row) * NROW + kw + c4 * 4);
        }
    };
    auto dmaB = [&](int it, ushort* Bb) {
        const int kw = kbeg + it * BK;
#pragma unroll
        for (int rr = 0; rr < 4; ++rr) {
            int P = w * 256 + rr * 64 + lane;    // linear 16B-chunk id (LDS side)
            int row = P >> 3;
            int pc = (P & 7) ^ (row & 7);        // fetch swizzled global chunk
            dma16(hT + (size_t)row * NROW + kw + pc * 8, Bb + (size_t)P * 8);
        }
    };
    auto storeA = [&](ushort* Abuf) {
#pragma unroll
        for (int rr = 0; rr < 8; ++rr) {
            int idx = rr * 256 + tid;
            int row = idx >> 4, c4 = idx & 15;
            int sw = (c4 >> 1) ^ (row & 7);      // 16B-chunk swizzle
            bf16x4 v;
            v[0] = (bf16_t)(va[rr].x * vm[rr].x);
            v[1] = (bf16_t)(va[rr].y * vm[rr].y);
            v[2] = (bf16_t)(va[rr].z * vm[rr].z);
            v[3] = (bf16_t)(va[rr].w * vm[rr].w);
            *(bf16x4*)(Abuf + row * 64 + sw * 8 + (c4 & 1) * 4) = v;
        }
    };
    auto compute = [&](const ushort* Abuf, const ushort* Bbuf) {
#pragma unroll
        for (int ss = 0; ss < 2; ++ss) {
            const int pc = ss * 4 + q;
            const int sw = pc ^ (m & 7);
            bf16x8 af[2];
#pragma unroll
            for (int r = 0; r < 2; ++r) {
                int row = w * 32 + r * 16 + m;   // row&7 == m&7
                af[r] = *(const bf16x8*)(Abuf + row * 64 + sw * 8);
            }
#pragma unroll
            for (int c = 0; c < 8; ++c) {
                int row = c * 16 + m;            // row&7 == m&7
                bf16x8 bv = *(const bf16x8*)(Bbuf + row * 64 + sw * 8);
#pragma unroll
                for (int r = 0; r < 2; ++r)
                    acc[r][c] = mfma16(af[r], bv, acc[r][c]);
            }
        }
    };

    // prologue: stage tile 0
    loadA(0);
    dmaB(0, Bb0);
    storeA(Ab0);

    for (int it = 0; it < NITER; ++it) {
        __syncthreads();                          // drains vmcnt (DMA) + lgkm
        const bool nx = (it + 1) < NITER;
        ushort* An = (it & 1) ? Ab0 : Ab1;
        ushort* Bn = (it & 1) ? Bb0 : Bb1;
        const ushort* Ac = (it & 1) ? Ab1 : Ab0;
        const ushort* Bc = (it & 1) ? Bb1 : Bb0;
        if (nx) { loadA(it + 1); dmaB(it + 1, Bn); }  // issue next-tile loads first
        compute(Ac, Bc);                               // MFMA hides load latency
        if (nx) storeA(An);                            // vmcnt wait + mul/cvt/ds_write
    }

    // epilogue: transpose acc through LDS for coalesced float4 stores
    __syncthreads();
    float* h_sl = (float*)lds_all + w * 4096;     // 16 KB private region per wave
#pragma unroll
    for (int r = 0; r < 2; ++r)
#pragma unroll
        for (int c = 0; c < 8; ++c)
#pragma unroll
            for (int j = 0; j < 4; ++j)
                h_sl[(r * 16 + q * 4 + j) * 128 + c * 16 + m] = acc[r][c][j];

    if (!ATOMIC) {
        float* dst = outp + (size_t)blockIdx.y * ((size_t)NROW * CD)
                   + (size_t)(rowbase + w * 32) * CD;
#pragma unroll
        for (int t = 0; t < 16; ++t) {
            int fi = t * 64 + lane;               // 1024 float4 = 32x128
            *(float4*)(dst + fi * 4) = *(const float4*)(h_sl + fi * 4);
        }
    } else {
        float* dst = outp + (size_t)(rowbase + w * 32) * CD;
        for (int t = 0; t < 64; ++t) {
            int ei = t * 64 + lane;
            atomicAdd(dst + ei, h_sl[ei]);
        }
    }
}

// out = out(h contribution) + sum over split-K partials
__global__ void reduce_kernel(float* __restrict__ out, const float* __restrict__ part)
{
    const size_t i = ((size_t)blockIdx.x * 256 + threadIdx.x) * 4;
    float4 sum = *(const float4*)(out + i);
#pragma unroll
    for (int sp = 0; sp < SPLITK; ++sp) {
        float4 p = *(const float4*)(part + (size_t)sp * ((size_t)NROW * CD) + i);
        sum.x += p.x; sum.y += p.y; sum.z += p.z; sum.w += p.w;
    }
    *(float4*)(out + i) = sum;
}

extern "C" void kernel_launch(void* const* d_in, const int* in_sizes, int n_in,
                              void* d_out, int out_size, void* d_ws, size_t ws_size,
                              hipStream_t stream)
{
    const float* x    = (const float*)d_in[0];
    const float* adj  = (const float*)d_in[1];
    const float* mask = (const float*)d_in[2];
    const float* W    = (const float*)d_in[3];
    float* out = (float*)d_out;

    bf16_t* hT = (bf16_t*)d_ws;  // 128 x 8192 bf16 = 2 MB
    const size_t HT_BYTES   = (size_t)CD * NROW * sizeof(bf16_t);
    const size_t PART_BYTES = (size_t)SPLITK * NROW * CD * sizeof(float);  // 32 MB

    h_kernel<<<dim3(NROW / 64), dim3(256), 0, stream>>>(x, W, hT, out);

    if (ws_size >= HT_BYTES + PART_BYTES) {
        float* part = (float*)((char*)d_ws + HT_BYTES);
        gemm_kernel<false><<<dim3(64, SPLITK), dim3(256), 0, stream>>>(adj, mask, hT, part);
        reduce_kernel<<<dim3(1024), dim3(256), 0, stream>>>(out, part);
    } else {
        gemm_kernel<true><<<dim3(64, SPLITK), dim3(256), 0, stream>>>(adj, mask, hT, out);
    }
}